// Round 2
// baseline (1323.709 us; speedup 1.0000x reference)
//
#include <hip/hip_runtime.h>

typedef unsigned short u16;
typedef __attribute__((ext_vector_type(8))) short short8;
typedef __attribute__((ext_vector_type(4))) float f32x4;

#define H   256
#define H2  512
#define TM  64
#define LNP 264   // LN tile row stride (elements), 16B-aligned rows, breaks bank stride
#define H1P 136   // h1 chunk row stride (elements), 16B-aligned rows

__device__ __forceinline__ u16 f2bf(float f) {
  unsigned int i = __builtin_bit_cast(unsigned int, f);
  unsigned int r = i + 0x7fffu + ((i >> 16) & 1u);
  return (u16)(r >> 16);
}
__device__ __forceinline__ float gelu_f(float x) {
  // jax.nn.gelu default: tanh approximation
  float x3 = x * x * x;
  float t = tanhf(0.7978845608028654f * (x + 0.044715f * x3));
  return 0.5f * x * (1.0f + t);
}

// Reorder a row-major K x Nw f32 weight matrix into bf16 MFMA B-fragment order:
// out[((n_tile*(K/32) + kk)*64 + lane)*8 + j] = bf16(W[(kk*32 + (lane>>4)*8 + j)*Nw + n_tile*16 + (lane&15)])
__global__ void reorder_w(const float* __restrict__ W, u16* __restrict__ out, int K, int Nw) {
  int tid = blockIdx.x * 256 + threadIdx.x;
  int total = K * Nw;
  if (tid >= total) return;
  int f = tid >> 9;          // fragment id
  int rsl = tid & 511;
  int lane = rsl >> 3, j = rsl & 7;
  int KK = K >> 5;
  int n_t = f / KK, kk = f - n_t * KK;
  int k = kk * 32 + (lane >> 4) * 8 + j;
  int n = n_t * 16 + (lane & 15);
  out[tid] = f2bf(W[(size_t)k * Nw + n]);
}

// Scatter-sum with run-accumulation (node_batch is sorted). Each thread: 4 cols x 8 nodes.
__global__ void seg_accum(const float* __restrict__ X, const int* __restrict__ batch,
                          float* __restrict__ ssum, float* __restrict__ scnt, int N) {
  int t = blockIdx.x * blockDim.x + threadIdx.x;
  int c4 = t & 63;
  int chunk = t >> 6;
  int n0 = chunk * 8;
  if (n0 >= N) return;
  int cols = c4 * 4;
  float a0 = 0.f, a1 = 0.f, a2 = 0.f, a3 = 0.f, cnt = 0.f;
  int curg = -1;
  for (int i = 0; i < 8; ++i) {
    int node = n0 + i;
    if (node >= N) break;
    int g = batch[node];
    if (g != curg) {
      if (curg >= 0) {
        atomicAdd(&ssum[curg * H + cols + 0], a0);
        atomicAdd(&ssum[curg * H + cols + 1], a1);
        atomicAdd(&ssum[curg * H + cols + 2], a2);
        atomicAdd(&ssum[curg * H + cols + 3], a3);
        if (c4 == 0) atomicAdd(&scnt[curg], cnt);
      }
      curg = g; a0 = a1 = a2 = a3 = 0.f; cnt = 0.f;
    }
    float4 u = *(const float4*)(X + (size_t)node * H + cols);
    a0 += u.x; a1 += u.y; a2 += u.z; a3 += u.w;
    cnt += 1.f;
  }
  if (curg >= 0) {
    atomicAdd(&ssum[curg * H + cols + 0], a0);
    atomicAdd(&ssum[curg * H + cols + 1], a1);
    atomicAdd(&ssum[curg * H + cols + 2], a2);
    atomicAdd(&ssum[curg * H + cols + 3], a3);
    if (c4 == 0) atomicAdd(&scnt[curg], cnt);
  }
}

__global__ void seg_finalize(const float* __restrict__ ssum, const float* __restrict__ scnt,
                             float* __restrict__ gfeat) {
  int i = blockIdx.x * 256 + threadIdx.x;   // G*H = 16384 threads
  float c = fmaxf(scnt[i >> 8], 1.0f);
  gfeat[i] = ssum[i] / c;
}

// Fused residual LayerNorm -> FFN(GELU) kernel. f32 I/O, bf16 MFMA internals.
// Block: 256 threads (4 waves), TM=64 rows. W1r/W2r are fragment-reordered bf16.
__global__ __launch_bounds__(256, 2) void ffn_kernel(
    const float* __restrict__ X, const float* __restrict__ gamma, const float* __restrict__ beta,
    const u16* __restrict__ w1r, const float* __restrict__ b1,
    const u16* __restrict__ w2r, const float* __restrict__ b2,
    float* __restrict__ Out, int M) {
  __shared__ __align__(16) u16 lnA[TM][LNP];
  __shared__ __align__(16) u16 h1s[TM][H1P];

  const int tid = threadIdx.x;
  const int row0 = blockIdx.x * TM;

  // ---- Phase 1: LayerNorm into LDS (bf16) ----
  {
    const int r = tid >> 2, p = tid & 3;
    const int row = row0 + r;
    float s = 0.f, ss = 0.f;
    const float4* xr = (const float4*)(X + (size_t)row * H + p * 64);
    float4 xv[16];
    if (row < M) {
#pragma unroll
      for (int i = 0; i < 16; ++i) {
        xv[i] = xr[i];
        float x0 = xv[i].x, x1 = xv[i].y, x2 = xv[i].z, x3 = xv[i].w;
        s += (x0 + x1) + (x2 + x3);
        ss += (x0 * x0 + x1 * x1) + (x2 * x2 + x3 * x3);
      }
    } else {
#pragma unroll
      for (int i = 0; i < 16; ++i) xv[i] = (float4){0.f, 0.f, 0.f, 0.f};
    }
    s += __shfl_xor(s, 1);  s += __shfl_xor(s, 2);
    ss += __shfl_xor(ss, 1); ss += __shfl_xor(ss, 2);
    const float mean = s * (1.f / H);
    const float var = ss * (1.f / H) - mean * mean;
    const float rstd = rsqrtf(var + 1e-5f);
#pragma unroll
    for (int i = 0; i < 16; ++i) {
      const int col = p * 64 + i * 4;
      float4 gv = ((const float4*)gamma)[col >> 2];
      float4 bv = ((const float4*)beta)[col >> 2];
      ushort4 o;
      o.x = f2bf((xv[i].x - mean) * rstd * gv.x + bv.x);
      o.y = f2bf((xv[i].y - mean) * rstd * gv.y + bv.y);
      o.z = f2bf((xv[i].z - mean) * rstd * gv.z + bv.z);
      o.w = f2bf((xv[i].w - mean) * rstd * gv.w + bv.w);
      *(ushort4*)&lnA[r][col] = o;
    }
  }
  __syncthreads();

  const int wave = tid >> 6, lane = tid & 63;
  const int lrow = lane & 15, q = lane >> 4;
  const int m0 = (wave >> 1) * 2;   // this wave's m-tile pair: {m0, m0+1}
  const int nh = (wave & 1);        // n-half selector

  // A1 fragments from LN tile: persist across all chunks (2m x 8kk)
  short8 a1[2][8];
#pragma unroll
  for (int m2 = 0; m2 < 2; ++m2) {
    const u16* ap = &lnA[(m0 + m2) * 16 + lrow][q * 8];
#pragma unroll
    for (int kk = 0; kk < 8; ++kk) a1[m2][kk] = *(const short8*)(ap + kk * 32);
  }

  // GEMM2 accumulators: 2m x 8n tiles, persist across chunks
  f32x4 acc[2][8];
#pragma unroll
  for (int m2 = 0; m2 < 2; ++m2)
#pragma unroll
    for (int nt = 0; nt < 8; ++nt) acc[m2][nt] = (f32x4){0.f, 0.f, 0.f, 0.f};

  for (int c = 0; c < 4; ++c) {
    // ---- GEMM1: produce gelu(h1) chunk (global cols [c*128, c*128+128)) ----
#pragma unroll
    for (int nt = 0; nt < 4; ++nt) {
      const int ng = c * 8 + nh * 4 + nt;   // global n-tile (0..31)
      f32x4 p0 = {0.f, 0.f, 0.f, 0.f}, p1 = {0.f, 0.f, 0.f, 0.f};
      const short8* bp = ((const short8*)w1r) + (size_t)(ng * 8) * 64 + lane;
#pragma unroll
      for (int kk = 0; kk < 8; ++kk) {
        short8 b = bp[(size_t)kk * 64];
        p0 = __builtin_amdgcn_mfma_f32_16x16x32_bf16(a1[0][kk], b, p0, 0, 0, 0);
        p1 = __builtin_amdgcn_mfma_f32_16x16x32_bf16(a1[1][kk], b, p1, 0, 0, 0);
      }
      const int colg = ng * 16 + lrow;
      const int coll = (nh * 4 + nt) * 16 + lrow;   // chunk-local col
      const float bias = b1[colg];
#pragma unroll
      for (int rr = 0; rr < 4; ++rr) {
        const int prow = q * 4 + rr;
        h1s[m0 * 16 + prow][coll] = f2bf(gelu_f(p0[rr] + bias));
        h1s[(m0 + 1) * 16 + prow][coll] = f2bf(gelu_f(p1[rr] + bias));
      }
    }
    __syncthreads();

    // ---- GEMM2 partial accumulate over this chunk's 4 k-tiles ----
    short8 a2[2][4];
#pragma unroll
    for (int m2 = 0; m2 < 2; ++m2) {
      const u16* ap = &h1s[(m0 + m2) * 16 + lrow][q * 8];
#pragma unroll
      for (int kk = 0; kk < 4; ++kk) a2[m2][kk] = *(const short8*)(ap + kk * 32);
    }
#pragma unroll
    for (int nt = 0; nt < 8; ++nt) {
      const int n = nh * 8 + nt;
      const short8* bp = ((const short8*)w2r) + (size_t)(n * 16 + c * 4) * 64 + lane;
#pragma unroll
      for (int kk = 0; kk < 4; ++kk) {
        short8 b = bp[(size_t)kk * 64];
        acc[0][nt] = __builtin_amdgcn_mfma_f32_16x16x32_bf16(a2[0][kk], b, acc[0][nt], 0, 0, 0);
        acc[1][nt] = __builtin_amdgcn_mfma_f32_16x16x32_bf16(a2[1][kk], b, acc[1][nt], 0, 0, 0);
      }
    }
    __syncthreads();
  }

  // ---- Epilogue: bias + residual, store f32 ----
#pragma unroll
  for (int nt = 0; nt < 8; ++nt) {
    const int col = (nh * 8 + nt) * 16 + lrow;
    const float bias = b2[col];
#pragma unroll
    for (int m2 = 0; m2 < 2; ++m2) {
#pragma unroll
      for (int rr = 0; rr < 4; ++rr) {
        const int lr = (m0 + m2) * 16 + q * 4 + rr;
        const int row = row0 + lr;
        if (row < M) {
          const size_t idx = (size_t)row * H + col;
          Out[idx] = acc[m2][nt][rr] + bias + X[idx];
        }
      }
    }
  }
}

extern "C" void kernel_launch(void* const* d_in, const int* in_sizes, int n_in,
                              void* d_out, int out_size, void* d_ws, size_t ws_size,
                              hipStream_t stream) {
  const float* nodeX = (const float*)d_in[0];
  const float* edgeX = (const float*)d_in[1];
  const int* batch = (const int*)d_in[2];
  // d_in[3] = num_graphs (G=64, fixed by problem)
  const float* n_g = (const float*)d_in[4];
  const float* n_b = (const float*)d_in[5];
  const float* n_w1 = (const float*)d_in[6];
  const float* n_b1 = (const float*)d_in[7];
  const float* n_w2 = (const float*)d_in[8];
  const float* n_b2 = (const float*)d_in[9];
  const float* g_g = (const float*)d_in[10];
  const float* g_b = (const float*)d_in[11];
  const float* g_w1 = (const float*)d_in[12];
  const float* g_b1 = (const float*)d_in[13];
  const float* g_w2 = (const float*)d_in[14];
  const float* g_b2 = (const float*)d_in[15];
  const float* e_g = (const float*)d_in[16];
  const float* e_b = (const float*)d_in[17];
  const float* e_w1 = (const float*)d_in[18];
  const float* e_b1 = (const float*)d_in[19];
  const float* e_w2 = (const float*)d_in[20];
  const float* e_b2 = (const float*)d_in[21];

  const int N = in_sizes[0] / H;    // 20000
  const int Me = in_sizes[1] / H;   // 320000
  const int G = 64;

  char* wsb = (char*)d_ws;
  u16* w1r_n = (u16*)(wsb + 0);
  u16* w2r_n = (u16*)(wsb + 262144);
  u16* w1r_g = (u16*)(wsb + 524288);
  u16* w2r_g = (u16*)(wsb + 786432);
  u16* w1r_e = (u16*)(wsb + 1048576);
  u16* w2r_e = (u16*)(wsb + 1310720);
  float* ssum = (float*)(wsb + 1572864);    // 64*256 f32
  float* scnt = (float*)(wsb + 1638400);    // 64 f32
  float* gfeat = (float*)(wsb + 1638656);   // 64*256 f32

  float* out_g = (float*)d_out;
  float* out_n = out_g + (size_t)G * H;
  float* out_e = out_n + (size_t)N * H;

  // Reorder all six weight matrices into MFMA B-fragment layout (tiny, L2-resident)
  reorder_w<<<512, 256, 0, stream>>>(n_w1, w1r_n, H, H2);
  reorder_w<<<512, 256, 0, stream>>>(n_w2, w2r_n, H2, H);
  reorder_w<<<512, 256, 0, stream>>>(g_w1, w1r_g, H, H2);
  reorder_w<<<512, 256, 0, stream>>>(g_w2, w2r_g, H2, H);
  reorder_w<<<512, 256, 0, stream>>>(e_w1, w1r_e, H, H2);
  reorder_w<<<512, 256, 0, stream>>>(e_w2, w2r_e, H2, H);

  // Scatter-mean for global features
  hipMemsetAsync(wsb + 1572864, 0, 65536 + 256, stream);
  {
    int chunks = (N + 7) / 8;
    int threads = chunks * 64;
    seg_accum<<<(threads + 255) / 256, 256, 0, stream>>>(nodeX, batch, ssum, scnt, N);
  }
  seg_finalize<<<64, 256, 0, stream>>>(ssum, scnt, gfeat);

  // Three FFN blocks
  ffn_kernel<<<(N + TM - 1) / TM, 256, 0, stream>>>(nodeX, n_g, n_b, w1r_n, n_b1, w2r_n, n_b2, out_n, N);
  ffn_kernel<<<(Me + TM - 1) / TM, 256, 0, stream>>>(edgeX, e_g, e_b, w1r_e, e_b1, w2r_e, e_b2, out_e, Me);
  ffn_kernel<<<1, 256, 0, stream>>>(gfeat, g_g, g_b, w1r_g, g_b1, w2r_g, g_b2, out_g, G);
}